// Round 11
// baseline (562.127 us; speedup 1.0000x reference)
//
#include <hip/hip_runtime.h>

typedef __bf16 bf16;
typedef __bf16 bf16x8 __attribute__((ext_vector_type(8)));
typedef float f32x4 __attribute__((ext_vector_type(4)));
typedef short s16x4 __attribute__((ext_vector_type(4)));

#define B_ 2
#define S_ 2048
#define D_ 2048
#define H_ 16
#define HKV_ 4
#define HD_ 128
#define QKVW 3072
#define QKW 2560                    // q+k columns (V handled separately)
#define SCALE 0.08838834764831845f  // 1/sqrt(128)
#define NEGINF -30000.0f            // finite -inf: exp underflows to 0, no inf-inf

// async global->LDS DMA, 16B per lane; LDS dest = wave-uniform base + lane*16
__device__ inline void gload16(const void* g, void* l) {
  __builtin_amdgcn_global_load_lds((const __attribute__((address_space(1))) unsigned int*)g,
                                   (__attribute__((address_space(3))) unsigned int*)l, 16, 0, 0);
}

__device__ inline unsigned short bfb(float v) {
  union { bf16 h; unsigned short u; } c;
  c.h = (bf16)v;
  return c.u;
}

// ---------------- dtype detection: bf16 or fp32 inputs? ----------------
__global__ void detect_dtype(const unsigned* __restrict__ xw, int* __restrict__ flag) {
  __shared__ int cnt;
  if (threadIdx.x == 0) cnt = 0;
  __syncthreads();
  unsigned w = xw[(size_t)threadIdx.x * 16384];
  unsigned low = w & 0xFFFFu;
  int e = (int)((low >> 7) & 0xFF);
  int vote = (low == 0u || (e >= 100 && e <= 140)) ? 1 : 0;
  atomicAdd(&cnt, vote);
  __syncthreads();
  if (threadIdx.x == 0) *flag = (cnt >= 128) ? 1 : 0;  // 1 = bf16, 0 = fp32
}

// ---------------- x -> bf16 pre-cast (into d_out scratch) ----------------
__global__ __launch_bounds__(256) void cast_x(const void* __restrict__ x,
                                              bf16* __restrict__ out,
                                              const int* __restrict__ flag) {
  int fm = *flag;
  long i = ((long)blockIdx.x * 256 + threadIdx.x) << 3;  // 8 elems/thread
  if (fm) {
    *(uint4*)(out + i) = *(const uint4*)((const bf16*)x + i);
  } else {
    const float* fp = (const float*)x + i;
    float4 a = *(const float4*)fp, b = *(const float4*)(fp + 4);
    alignas(16) bf16 t[8];
    t[0] = (bf16)a.x; t[1] = (bf16)a.y; t[2] = (bf16)a.z; t[3] = (bf16)a.w;
    t[4] = (bf16)b.x; t[5] = (bf16)b.y; t[6] = (bf16)b.z; t[7] = (bf16)b.w;
    *(uint4*)(out + i) = *(uint4*)t;
  }
}

// ---------------- fused Wq/Wk/Wv transpose -> wqkvT (B^T layout) ----------------
__global__ __launch_bounds__(256) void transpose_qkvw(
    const void* __restrict__ Wq, const void* __restrict__ Wk, const void* __restrict__ Wv,
    bf16* __restrict__ wqkvT, const int* __restrict__ flag) {
  int z = blockIdx.z;
  const void* in = (z == 0) ? Wq : (z == 1) ? Wk : Wv;
  int cols = (z == 0) ? 2048 : 512;
  bf16* out = wqkvT + ((z == 0) ? 0 : (z == 1) ? 2048 * 2048 : 2560 * 2048);
  if (blockIdx.x * 32 >= cols) return;
  int fm = *flag;
  __shared__ float tile[32][33];
  int c0 = blockIdx.x * 32, r0 = blockIdx.y * 32;
  int tx = threadIdx.x, ty = threadIdx.y;  // 32 x 8
#pragma unroll
  for (int i = 0; i < 32; i += 8) {
    long idx = (long)(r0 + ty + i) * cols + c0 + tx;
    tile[ty + i][tx] = fm ? (float)((const bf16*)in)[idx] : ((const float*)in)[idx];
  }
  __syncthreads();
#pragma unroll
  for (int i = 0; i < 32; i += 8)
    out[(long)(c0 + ty + i) * 2048 + r0 + tx] = (bf16)tile[tx][ty + i];
}

// ---------------- generic transpose (+dtype-adaptive read) for Wo ----------------
__global__ __launch_bounds__(256) void transpose_cvt(
    const void* __restrict__ in, bf16* __restrict__ out,
    long in_stride, long out_stride, const int* __restrict__ flag) {
  __shared__ float tile[32][33];
  int fm = *flag;
  int c0 = blockIdx.x * 32, r0 = blockIdx.y * 32;
  int tx = threadIdx.x, ty = threadIdx.y;
#pragma unroll
  for (int i = 0; i < 32; i += 8) {
    long idx = (long)(r0 + ty + i) * in_stride + c0 + tx;
    tile[ty + i][tx] = fm ? (float)((const bf16*)in)[idx] : ((const float*)in)[idx];
  }
  __syncthreads();
#pragma unroll
  for (int i = 0; i < 32; i += 8)
    out[(long)(c0 + ty + i) * out_stride + r0 + tx] = (bf16)tile[tx][ty + i];
}

// ---------------- GEMM (gemm2 config): C = A * Bt^T, 128x128, 256 thr ----------------
// Proven: 2-phase dbuf, BK=32, 32 KB LDS, one __syncthreads per K-step, mod-4
// rotation swizzle both-sides (bank conflicts = 0), T1 XCD swizzle.
#define BM 128
#define BN 128
#define BK 32

__global__ __launch_bounds__(256) void gemm_bt(
    const void* __restrict__ A, const bf16* __restrict__ Bt, void* __restrict__ C,
    int M, int N, int K, int ldc, int ncmax,
    bf16* __restrict__ vt_out, int vcol0,
    const int* __restrict__ flag, int adyn, int cdyn) {
  alignas(16) __shared__ bf16 la[2 * BM * BK];  // 2 x 8 KB, unpadded (DMA lane-linear)
  alignas(16) __shared__ bf16 lb[2 * BN * BK];  // 2 x 8 KB
  int fm = flag ? *flag : 1;
  bool af32 = adyn && !fm;
  bool cf32 = cdyn && !fm;
  int tid = threadIdx.x;
  int wave = tid >> 6, lane = tid & 63;
  int wr = wave >> 1, wc = wave & 1;
  int quad = lane >> 4, l16 = lane & 15;

  // T1: XCD-aware block swizzle (nwg % 8 == 0 for both launches)
  int nwg = (int)(gridDim.x * gridDim.y);
  int flat = (int)(blockIdx.y * gridDim.x + blockIdx.x);
  int cpx = nwg >> 3;
  int wk = (flat & 7) * cpx + (flat >> 3);
  int bx = wk % (int)gridDim.x, by = wk / (int)gridDim.x;
  int m0 = by * BM, n0 = bx * BN;

  f32x4 acc[4][4] = {};

  int sr = (wave << 4) + (lane >> 2);
  int sc = (((lane & 3) - (sr >> 1)) & 3) << 3;  // rotated source chunk (elems)
  const bf16* gb0 = Bt + (long)(n0 + sr) * K + sc;
  const bf16* gb1 = Bt + (long)(n0 + 64 + sr) * K + sc;
  int lo0 = (wave << 9);
  int lo1 = 2048 + (wave << 9);
  const bf16* ga0 = nullptr; const bf16* ga1 = nullptr;
  const float* gaf = nullptr;
  int fr = tid >> 1, fh = (tid & 1) << 4;
  if (af32) gaf = (const float*)A + (long)(m0 + fr) * K + fh;
  else { ga0 = (const bf16*)A + (long)(m0 + sr) * K + sc;
         ga1 = (const bf16*)A + (long)(m0 + 64 + sr) * K + sc; }
  int c0 = fh >> 3;
  int k2 = (fr >> 1) & 3;
  int ws0 = ((c0 + k2) & 3) << 3;
  int ws1 = ((c0 + 1 + k2) & 3) << 3;

  int nk = K / BK;

  auto cvtwrite = [&](const float4* f, int buf) {
    alignas(16) bf16 tt[16];
#pragma unroll
    for (int u = 0; u < 4; u++) {
      tt[4 * u] = (bf16)f[u].x; tt[4 * u + 1] = (bf16)f[u].y;
      tt[4 * u + 2] = (bf16)f[u].z; tt[4 * u + 3] = (bf16)f[u].w;
    }
    bf16* rowp = la + (buf << 12) + fr * BK;
    *(uint4*)(rowp + ws0) = *(uint4*)tt;
    *(uint4*)(rowp + ws1) = *(uint4*)(tt + 8);
  };
  auto compute = [&](int buf) {
    const bf16* baA = la + (buf << 12);
    const bf16* baB = lb + (buf << 12);
    bf16x8 afr[4], bfr[4];
#pragma unroll
    for (int i = 0; i < 4; i++) {
      int rowA = (wr << 6) + (i << 4) + l16;
      afr[i] = *(const bf16x8*)(baA + rowA * BK + (((quad + (rowA >> 1)) & 3) << 3));
    }
#pragma unroll
    for (int j = 0; j < 4; j++) {
      int rowB = (wc << 6) + (j << 4) + l16;
      bfr[j] = *(const bf16x8*)(baB + rowB * BK + (((quad + (rowB >> 1)) & 3) << 3));
    }
#pragma unroll
    for (int i = 0; i < 4; i++)
#pragma unroll
      for (int j = 0; j < 4; j++)
        acc[i][j] = __builtin_amdgcn_mfma_f32_16x16x32_bf16(afr[i], bfr[j], acc[i][j], 0, 0, 0);
  };

  gload16(gb0, lb + lo0);
  gload16(gb1, lb + lo1);
  if (af32) {
    float4 f0[4];
#pragma unroll
    for (int u = 0; u < 4; u++) f0[u] = *(const float4*)(gaf + 4 * u);
    cvtwrite(f0, 0);
  } else {
    gload16(ga0, la + lo0);
    gload16(ga1, la + lo1);
  }
  __syncthreads();

  for (int t = 0; t < nk; ++t) {
    int cur = t & 1, nxt = cur ^ 1;
    bool hasnext = (t + 1 < nk);
    float4 f[4];
    if (hasnext) {
      int k0 = (t + 1) * BK;
      gload16(gb0 + k0, lb + (nxt << 12) + lo0);
      gload16(gb1 + k0, lb + (nxt << 12) + lo1);
      if (af32) {
        const float* fp = gaf + k0;
#pragma unroll
        for (int u = 0; u < 4; u++) f[u] = *(const float4*)(fp + 4 * u);
      } else {
        gload16(ga0 + k0, la + (nxt << 12) + lo0);
        gload16(ga1 + k0, la + (nxt << 12) + lo1);
      }
    }

    compute(cur);

    if (hasnext && af32) cvtwrite(f, nxt);
    __syncthreads();
  }

  if (vt_out && n0 >= vcol0) {
#pragma unroll
    for (int i = 0; i < 4; i++)
#pragma unroll
      for (int j = 0; j < 4; j++) {
        int col = n0 + (wc << 6) + (j << 4) + l16;
        int hdg = col - vcol0;
        int row0 = m0 + (wr << 6) + (i << 4) + (quad << 2);
        int bb = row0 >> 11, s = row0 & 2047;
        ushort4 p;
        p.x = bfb(acc[i][j][0]); p.y = bfb(acc[i][j][1]);
        p.z = bfb(acc[i][j][2]); p.w = bfb(acc[i][j][3]);
        *(ushort4*)(vt_out + (((long)(bb * 512 + hdg)) << 11) + s) = p;
      }
  } else {
#pragma unroll
    for (int i = 0; i < 4; i++)
#pragma unroll
      for (int j = 0; j < 4; j++) {
        int col = n0 + (wc << 6) + (j << 4) + l16;
        if (col >= ncmax) continue;
#pragma unroll
        for (int r = 0; r < 4; r++) {
          long row = m0 + (wr << 6) + (i << 4) + (quad << 2) + r;
          float v = acc[i][j][r];
          if (cf32) ((float*)C)[row * ldc + col] = v;
          else      ((bf16*)C)[row * ldc + col] = (bf16)v;
        }
      }
  }
}

// ---------------- GEMM wide (gemm1): 128M x 256N, BK=32, 512 thr / 8 waves ----------------
// A is always bf16 (pre-cast by cast_x) -> pure-DMA A path.
#define WBM 128
#define WBN 256
#define WBK 32

__global__ __launch_bounds__(512, 4) void gemm_bt_wide(
    const void* __restrict__ A, const bf16* __restrict__ Bt, bf16* __restrict__ C,
    int K, int ldc, int ncmax,
    bf16* __restrict__ vt_out, int vcol0, const int* __restrict__ flag) {
  alignas(16) __shared__ bf16 la[2 * WBM * WBK];  // 2 x 8 KB
  alignas(16) __shared__ bf16 lb[2 * WBN * WBK];  // 2 x 16 KB  (48 KB total)
  int fm = flag ? *flag : 1;
  bool af32 = !fm;  // flag=nullptr at call site -> always bf16 path
  int tid = threadIdx.x;
  int wave = tid >> 6, lane = tid & 63;
  int wm = wave >> 2, wn = wave & 3;  // 2M x 4N wave grid
  int quad = lane >> 4, l16 = lane & 15;

  // T1: XCD-aware block swizzle (384 % 8 == 0)
  int nwg = (int)(gridDim.x * gridDim.y);
  int flat = (int)(blockIdx.y * gridDim.x + blockIdx.x);
  int cpx = nwg >> 3;
  int wk = (flat & 7) * cpx + (flat >> 3);
  int bx = wk % (int)gridDim.x, by = wk / (int)gridDim.x;
  int m0 = by * WBM, n0 = bx * WBN;

  f32x4 acc[4][4] = {};

  const bf16* gb[2];
  int lbo[2];
#pragma unroll
  for (int u = 0; u < 2; u++) {
    int sr2 = (wave << 5) + (u << 4) + (lane >> 2);
    int sc2 = (((lane & 3) - (sr2 >> 1)) & 3) << 3;  // rotated source chunk
    gb[u] = Bt + (long)(n0 + sr2) * K + sc2;
    lbo[u] = ((wave << 5) + (u << 4)) << 5;  // row_base * 32 elems (lane-linear dest)
  }
  const bf16* gaB = nullptr;
  const float* gaf = nullptr;
  int lao = (wave << 4) << 5;
  int fr = tid >> 2, fc = tid & 3;
  int wso = 0;
  if (af32) {
    gaf = (const float*)A + (long)(m0 + fr) * K + (fc << 3);
    wso = (fr << 5) + ((((fc) + (fr >> 1)) & 3) << 3);
  } else {
    int ra = (wave << 4) + (lane >> 2);
    int sca = (((lane & 3) - (ra >> 1)) & 3) << 3;
    gaB = (const bf16*)A + (long)(m0 + ra) * K + sca;
  }

  int nk = K / WBK;

  auto cvtwrite = [&](const float4* f, int buf) {
    alignas(16) bf16 tt[8];
    tt[0] = (bf16)f[0].x; tt[1] = (bf16)f[0].y; tt[2] = (bf16)f[0].z; tt[3] = (bf16)f[0].w;
    tt[4] = (bf16)f[1].x; tt[5] = (bf16)f[1].y; tt[6] = (bf16)f[1].z; tt[7] = (bf16)f[1].w;
    *(uint4*)(la + (buf << 12) + wso) = *(uint4*)tt;
  };
  auto compute = [&](int buf) {
    const bf16* baA = la + (buf << 12);
    const bf16* baB = lb + (buf << 13);
    bf16x8 afr[4], bfr[4];
#pragma unroll
    for (int i = 0; i < 4; i++) {
      int rowA = (wm << 6) + (i << 4) + l16;
      afr[i] = *(const bf16x8*)(baA + (rowA << 5) + (((quad + (rowA >> 1)) & 3) << 3));
    }
#pragma unroll
    for (int j = 0; j < 4; j++) {
      int rowB = (wn << 6) + (j << 4) + l16;
      bfr[j] = *(const bf16x8*)(baB + (rowB << 5) + (((quad + (rowB >> 1)) & 3) << 3));
    }
#pragma unroll
    for (int i = 0; i < 4; i++)
#pragma unroll
      for (int j = 0; j < 4; j++)
        acc[i][j] = __builtin_amdgcn_mfma_f32_16x16x32_bf16(afr[i], bfr[j], acc[i][j], 0, 0, 0);
  };

  // ---- prologue ----
  gload16(gb[0], lb + lbo[0]);
  gload16(gb[1], lb + lbo[1]);
  if (af32) {
    float4 f0[2];
    f0[0] = *(const float4*)gaf;
    f0[1] = *(const float4*)(gaf + 4);
    cvtwrite(f0, 0);
  } else {
    gload16(gaB, la + lao);
  }
  __syncthreads();

  // ---- main loop ----
  for (int t = 0; t < nk; ++t) {
    int cur = t & 1, nxt = cur ^ 1;
    bool hasnext = (t + 1 < nk);
    float4 f[2];
    if (hasnext) {
      int k0 = (t + 1) * WBK;
      gload16(gb[0] + k0, lb + (nxt << 13) + lbo[0]);
      gload16(gb[1] + k0, lb + (nxt << 13) + lbo[1]);
      if (af32) {
        f[0] = *(const float4*)(gaf + k0);
        f[1] = *(const float4*)(gaf + k0 + 4);
      } else {
        gload16(gaB + k0, la + (nxt << 12) + lao);
      }
    }

    compute(cur);

    if (hasnext && af32) cvtwrite(f, nxt);
    __syncthreads();
  }

  if (vt_out && n0 >= vcol0) {
#pragma unroll
    for (int i = 0; i < 4; i++)
#pragma unroll
      for (int j = 0; j < 4; j++) {
        int col = n0 + (wn << 6) + (j << 4) + l16;
        int hdg = col - vcol0;                            // 0..511 = kh*128+hd
        int row0 = m0 + (wm << 6) + (i << 4) + (quad << 2);
        int bb = row0 >> 11, s = row0 & 2047;
        ushort4 p;
        p.x = bfb(acc[i][j][0]); p.y = bfb(acc[i][j][1]);
        p.z = bfb(acc[i][j][2]); p.w = bfb(acc[i][j][3]);
        *(ushort4*)(vt_out + (((long)(bb * 512 + hdg)) << 11) + s) = p;
      }
  } else {
#pragma unroll
    for (int i = 0; i < 4; i++)
#pragma unroll
      for (int j = 0; j < 4; j++) {
        int col = n0 + (wn << 6) + (j << 4) + l16;
        if (col >= ncmax) continue;
#pragma unroll
        for (int r = 0; r < 4; r++) {
          long row = m0 + (wm << 6) + (i << 4) + (quad << 2) + r;
          C[row * ldc + col] = (bf16)acc[i][j][r];
        }
      }
  }
}

// ---------------- RoPE + scatter (Q pre-scaled by 1/sqrt(d)) ----------------
__global__ __launch_bounds__(256) void rope_scatter(
    const bf16* __restrict__ qkv, bf16* __restrict__ Q, bf16* __restrict__ Ko) {
  int row = blockIdx.x;  // b*S + s
  int b = row >> 11, s = row & 2047;
  int tid = threadIdx.x;
  int i = tid & 63;
  const bf16* src = qkv + (long)row * QKW;
  float theta = __expf(-0.14391156831212787f * (float)i);  // 10000^(-2i/128)
  float sn, cs;
  sincosf((float)s * theta, &sn, &cs);
#pragma unroll
  for (int it = 0; it < 4; ++it) {
    int h = (tid + it * 256) >> 6;  // 0..15 over the 4 iterations
    unsigned v = *(const unsigned*)(src + h * 128 + 2 * i);
    float x1 = __uint_as_float(v << 16);
    float x2 = __uint_as_float(v & 0xFFFF0000u);
    long qb = ((long)(b * H_ + h) * S_ + s) * HD_;
    Q[qb + i]      = (bf16)((x1 * cs - x2 * sn) * SCALE);
    Q[qb + 64 + i] = (bf16)((x1 * sn + x2 * cs) * SCALE);
  }
  {
    int kh = tid >> 6;
    unsigned v = *(const unsigned*)(src + 2048 + kh * 128 + 2 * i);
    float x1 = __uint_as_float(v << 16);
    float x2 = __uint_as_float(v & 0xFFFF0000u);
    long kb = ((long)(b * HKV_ + kh) * S_ + s) * HD_;
    Ko[kb + i]      = (bf16)(x1 * cs - x2 * sn);
    Ko[kb + 64 + i] = (bf16)(x1 * sn + x2 * cs);
  }
}

// ---------------- flash attention ----------------
// v2: V is NOT LDS-staged (per-XCD V working set = 0.5 MB, L2-resident; staging
// L2-fit data is pure overhead). PV A-operand reads global directly -- the old
// LDS XOR-swizzle cancels against the DMA source swizzle, leaving
// Vg + v*S + kt*64 + jb*16 + quad*4. LDS = K dbuf only (32 KB).
// Grid un-paired to 1024 blocks (one q-tile each) -> 4 blocks/CU, ALL co-resident
// (16 waves/CU, 2x the paired version). Per-CU balance: the 4 blocks a CU hosts
// (j, j+8, j+16, j+24) map to qt {lo, 15-lo, 16+lo, 31-lo} -> constant 66 tiles.
// XCD partition kept: blockIdx%8 = b*4+kh.
#define KTILE 8192  // 64 rows x 128 elems

__global__ __launch_bounds__(256, 4) void attn_kernel(
    const bf16* __restrict__ Q, const bf16* __restrict__ K,
    const bf16* __restrict__ Vt, bf16* __restrict__ O) {
  alignas(16) __shared__ bf16 Ks[2 * KTILE];  // 32 KB (K dbuf only)
  int bi = (int)blockIdx.x;        // 1024 blocks, 1-D
  int cb = bi & 7;                 // XCD selector = (b, kh)
  int b = cb >> 2, kh = cb & 3;
  int r = bi >> 3;                 // 0..127
  int h = kh * 4 + (r & 3);
  int j = r >> 2;                  // 0..31
  int lo = j & 7, hi = j >> 3;
  int qt = (hi == 0) ? lo : (hi == 1) ? 15 - lo : (hi == 2) ? 16 + lo : 31 - lo;
  int q0 = qt * 64;
  int tid = threadIdx.x, wave = tid >> 6, lane = tid & 63;
  int quad = lane >> 4, l16 = lane & 15;
  const bf16* Kg = K + ((long)(b * HKV_ + kh) * S_) * HD_;
  const bf16* Vg = Vt + ((long)(b * HKV_ + kh) * HD_) * S_;

  // K DMA offsets (elems): 16 calls/tile, call i = u*4+wave covers flat chunks
  // [i*64, i*64+64); chunk f: lane = f&63, r=f>>4, c=(f&15)^(r&15) (XOR source swizzle).
  int kgo[4], klo[4];
#pragma unroll
  for (int u = 0; u < 4; u++) {
    int i = u * 4 + wave;
    int rr = i * 4 + quad;
    int c = l16 ^ (rr & 15);
    kgo[u] = rr * HD_ + c * 8;
    klo[u] = i * 512;
  }

  const bf16* Qg = Q + ((long)(b * H_ + h) * S_ + q0) * HD_;
  // Q B-fragments in registers (pre-scaled by 1/sqrt(d)); lane l16 = qrow
  bf16x8 qb[4];
  {
    const bf16* qrow = Qg + (wave * 16 + l16) * HD_ + quad * 8;
#pragma unroll
    for (int kk = 0; kk < 4; kk++) qb[kk] = *(const bf16x8*)(qrow + kk * 32);
  }

  // preload K tile 0 into buffer 0
#pragma unroll
  for (int u = 0; u < 4; u++) gload16(Kg + kgo[u], Ks + klo[u]);

  // per-lane V row base: row (l16 + n*16), col (quad*4); + kt*64 per tile
  const bf16* vrow = Vg + (long)l16 * S_ + quad * 4;

  f32x4 Of[8] = {};                   // O^T: col l16 = qrow, rows = hd
  float m_run = NEGINF, l_run = 0.f;  // per-lane state for qrow (wave*16 + l16)

  for (int kt = 0; kt <= qt; ++kt) {
    __syncthreads();  // drains DMA for buf (kt&1); prior readers of buf (kt&1)^1 done
    int p = kt & 1;
    if (kt < qt) {  // issue next-tile K DMA into idle buffer
      const bf16* kn = Kg + (long)(kt + 1) * 8192;
      bf16* kd = Ks + (p ^ 1) * KTILE;
#pragma unroll
      for (int u = 0; u < 4; u++) gload16(kn + kgo[u], kd + klo[u]);
    }
    const bf16* kc = Ks + p * KTILE;

    // S^T = K Q^T: A = K-frag (m = key), B = Q-frag (n = qrow)
    bool diag = (kt == qt);
    f32x4 sf[4];
    __builtin_amdgcn_s_setprio(1);  // T5: favor MFMA-issuing wave
#pragma unroll
    for (int jb = 0; jb < 4; jb++) {
      if (diag && jb > wave) {  // fully-masked key block on diagonal tile
        sf[jb] = (f32x4){NEGINF, NEGINF, NEGINF, NEGINF};
      } else {
        f32x4 a = {};
        const bf16* kbase = kc + (jb * 16 + l16) * 128;
#pragma unroll
        for (int kk = 0; kk < 4; kk++) {
          bf16x8 kf = *(const bf16x8*)(kbase + (((kk * 4 + quad) ^ l16) * 8));
          a = __builtin_amdgcn_mfma_f32_16x16x32_bf16(kf, qb[kk], a, 0, 0, 0);
        }
        sf[jb] = a;
      }
    }
    __builtin_amdgcn_s_setprio(0);
    if (diag) {  // partial mask on key block jb == wave (constant indices only)
#pragma unroll
      for (int jb = 0; jb < 4; jb++)
        if (jb == wave) {
#pragma unroll
          for (int r2 = 0; r2 < 4; r2++)
            if (quad * 4 + r2 > l16) sf[jb][r2] = NEGINF;
        }
    }

    // per-lane row max + 2 cross-quad shuffles
    float mx = NEGINF;
#pragma unroll
    for (int jb = 0; jb < 4; jb++)
#pragma unroll
      for (int r2 = 0; r2 < 4; r2++) mx = fmaxf(mx, sf[jb][r2]);
    mx = fmaxf(mx, __shfl_xor(mx, 16));
    mx = fmaxf(mx, __shfl_xor(mx, 32));
    // T13 defer-max
    if (__any(mx > m_run + 8.0f)) {
      float mnew = fmaxf(m_run, mx);
      float alpha = __expf(m_run - mnew);
      m_run = mnew;
      l_run *= alpha;
#pragma unroll
      for (int n = 0; n < 8; n++) Of[n] *= alpha;
    }

    // p = exp(s - m): stays in registers as the PV B-operand
    float ls = 0.f;
    s16x4 pk[4];
#pragma unroll
    for (int jb = 0; jb < 4; jb++) {
      float p0 = __expf(sf[jb][0] - m_run);
      float p1 = __expf(sf[jb][1] - m_run);
      float p2 = __expf(sf[jb][2] - m_run);
      float p3 = __expf(sf[jb][3] - m_run);
      ls += (p0 + p1) + (p2 + p3);
      s16x4 t;
      t.x = (short)bfb(p0); t.y = (short)bfb(p1);
      t.z = (short)bfb(p2); t.w = (short)bfb(p3);
      pk[jb] = t;
    }
    l_run += ls;

    // O^T += V^T P^T via 16x16x16 MFMA; A = V^T frag DIRECT FROM GLOBAL (L2-resident)
    __builtin_amdgcn_s_setprio(1);
    {
      const bf16* vb = vrow + kt * 64;
#pragma unroll
      for (int n = 0; n < 8; n++) {
        const bf16* vn = vb + (long)(n * 16) * S_;
#pragma unroll
        for (int jb = 0; jb < 4; jb++) {
          if (diag && jb > wave) continue;  // p == 0
          s16x4 va = *(const s16x4*)(vn + jb * 16);
          Of[n] = __builtin_amdgcn_mfma_f32_16x16x16bf16_1k(va, pk[jb], Of[n], 0, 0, 0);
        }
      }
    }
    __builtin_amdgcn_s_setprio(0);
  }

  // epilogue: reduce l across quads, packed 8B stores
  l_run += __shfl_xor(l_run, 16);
  l_run += __shfl_xor(l_run, 32);
  float inv = 1.0f / fmaxf(l_run, 1e-30f);
  bf16* Ob = O + ((long)(b * S_) + q0 + wave * 16 + l16) * D_ + h * HD_;
#pragma unroll
  for (int n = 0; n < 8; n++) {
    ushort4 w;
    w.x = bfb(Of[n][0] * inv); w.y = bfb(Of[n][1] * inv);
    w.z = bfb(Of[n][2] * inv); w.w = bfb(Of[n][3] * inv);
    *(ushort4*)(Ob + n * 16 + quad * 4) = w;
  }
}

// ---------------- launch ----------------
extern "C" void kernel_launch(void* const* d_in, const int* in_sizes, int n_in,
                              void* d_out, int out_size, void* d_ws, size_t ws_size,
                              hipStream_t stream) {
  const void* x  = d_in[0];
  const void* Wq = d_in[1];
  const void* Wk = d_in[2];
  const void* Wv = d_in[3];
  const void* Wo = d_in[4];
  bf16* ws = (bf16*)d_ws;
  int* flag = (int*)d_ws;

  // workspace (bf16 elem offsets), peak 23,068,688 elems = 46.1 MB (proven)
  bf16* qkv   = ws + 16;        // 4096 x 2560          gemm1 -> rope
  bf16* Vtb   = ws + 10485776;  // 2 x 512 x 2048       gemm1 epilogue -> attn
  bf16* Qb    = ws + 12582928;  // 2x16x2048x128        rope -> attn
  bf16* wqkvT = ws + 12582928;  // 3072x2048 (overlaps Qb; dead before rope writes)
  bf16* Kb    = ws + 20971536;  // 2x4x2048x128         rope -> attn
  bf16* attno = ws + 16;        // reuse qkv            attn -> gemm2
  bf16* woT   = ws + 10485776;  // reuse Vtb/Qb region  (transposed after attn)
  bf16* xb    = (bf16*)d_out;   // x in bf16 (d_out scratch; dead before gemm2 writes)

  dim3 tb(32, 8);
  detect_dtype<<<1, 256, 0, stream>>>((const unsigned*)x, flag);
  cast_x<<<4096, 256, 0, stream>>>(x, xb, flag);
  transpose_qkvw<<<dim3(64, 64, 3), tb, 0, stream>>>(Wq, Wk, Wv, wqkvT, flag);
  // qkv = xb @ [Wq|Wk|Wv]; q,k cols -> qkv (ldc 2560), v cols -> Vtb transposed
  gemm_bt_wide<<<dim3(QKVW / WBN, (B_ * S_) / WBM), 512, 0, stream>>>(
      xb, wqkvT, qkv, D_, QKW, QKW, Vtb, QKW, nullptr);
  rope_scatter<<<B_ * S_, 256, 0, stream>>>(qkv, Qb, Kb);
  // un-paired 1-D grid: 1024 blocks; low 3 bits = (b,kh) -> XCD partition;
  // qt mapping makes each CU's 4 resident blocks sum to a constant 66 tiles
  attn_kernel<<<dim3(1024, 1, 1), 256, 0, stream>>>(Qb, Kb, Vtb, attno);
  transpose_cvt<<<dim3(64, 64, 1), tb, 0, stream>>>(Wo, woT, 2048, 2048, flag);
  // out = attno @ Wo (output dtype per flag); overwrites xb scratch (dead by now)
  gemm_bt<<<dim3(D_ / BN, (B_ * S_) / BM), 256, 0, stream>>>(
      attno, woT, d_out, B_ * S_, D_, D_, D_, D_, nullptr, 0, flag, 0, 1);
}

// Round 12
// 379.793 us; speedup vs baseline: 1.4801x; 1.4801x over previous
//
#include <hip/hip_runtime.h>

typedef __bf16 bf16;
typedef __bf16 bf16x8 __attribute__((ext_vector_type(8)));
typedef float f32x4 __attribute__((ext_vector_type(4)));
typedef short s16x4 __attribute__((ext_vector_type(4)));

#define B_ 2
#define S_ 2048
#define D_ 2048
#define H_ 16
#define HKV_ 4
#define HD_ 128
#define QKVW 3072
#define QKW 2560                    // q+k columns (V handled separately)
#define SCALE 0.08838834764831845f  // 1/sqrt(128)
#define NEGINF -30000.0f            // finite -inf: exp underflows to 0, no inf-inf

// async global->LDS DMA, 16B per lane; LDS dest = wave-uniform base + lane*16
__device__ inline void gload16(const void* g, void* l) {
  __builtin_amdgcn_global_load_lds((const __attribute__((address_space(1))) unsigned int*)g,
                                   (__attribute__((address_space(3))) unsigned int*)l, 16, 0, 0);
}

__device__ inline unsigned short bfb(float v) {
  union { bf16 h; unsigned short u; } c;
  c.h = (bf16)v;
  return c.u;
}

// ---------------- dtype detection: bf16 or fp32 inputs? ----------------
__global__ void detect_dtype(const unsigned* __restrict__ xw, int* __restrict__ flag) {
  __shared__ int cnt;
  if (threadIdx.x == 0) cnt = 0;
  __syncthreads();
  unsigned w = xw[(size_t)threadIdx.x * 16384];
  unsigned low = w & 0xFFFFu;
  int e = (int)((low >> 7) & 0xFF);
  int vote = (low == 0u || (e >= 100 && e <= 140)) ? 1 : 0;
  atomicAdd(&cnt, vote);
  __syncthreads();
  if (threadIdx.x == 0) *flag = (cnt >= 128) ? 1 : 0;  // 1 = bf16, 0 = fp32
}

// ---------------- x -> bf16 pre-cast (into d_out scratch) ----------------
__global__ __launch_bounds__(256) void cast_x(const void* __restrict__ x,
                                              bf16* __restrict__ out,
                                              const int* __restrict__ flag) {
  int fm = *flag;
  long i = ((long)blockIdx.x * 256 + threadIdx.x) << 3;  // 8 elems/thread
  if (fm) {
    *(uint4*)(out + i) = *(const uint4*)((const bf16*)x + i);
  } else {
    const float* fp = (const float*)x + i;
    float4 a = *(const float4*)fp, b = *(const float4*)(fp + 4);
    alignas(16) bf16 t[8];
    t[0] = (bf16)a.x; t[1] = (bf16)a.y; t[2] = (bf16)a.z; t[3] = (bf16)a.w;
    t[4] = (bf16)b.x; t[5] = (bf16)b.y; t[6] = (bf16)b.z; t[7] = (bf16)b.w;
    *(uint4*)(out + i) = *(uint4*)t;
  }
}

// ---------------- fused Wq/Wk/Wv transpose -> wqkvT (B^T layout) ----------------
__global__ __launch_bounds__(256) void transpose_qkvw(
    const void* __restrict__ Wq, const void* __restrict__ Wk, const void* __restrict__ Wv,
    bf16* __restrict__ wqkvT, const int* __restrict__ flag) {
  int z = blockIdx.z;
  const void* in = (z == 0) ? Wq : (z == 1) ? Wk : Wv;
  int cols = (z == 0) ? 2048 : 512;
  bf16* out = wqkvT + ((z == 0) ? 0 : (z == 1) ? 2048 * 2048 : 2560 * 2048);
  if (blockIdx.x * 32 >= cols) return;
  int fm = *flag;
  __shared__ float tile[32][33];
  int c0 = blockIdx.x * 32, r0 = blockIdx.y * 32;
  int tx = threadIdx.x, ty = threadIdx.y;  // 32 x 8
#pragma unroll
  for (int i = 0; i < 32; i += 8) {
    long idx = (long)(r0 + ty + i) * cols + c0 + tx;
    tile[ty + i][tx] = fm ? (float)((const bf16*)in)[idx] : ((const float*)in)[idx];
  }
  __syncthreads();
#pragma unroll
  for (int i = 0; i < 32; i += 8)
    out[(long)(c0 + ty + i) * 2048 + r0 + tx] = (bf16)tile[tx][ty + i];
}

// ---------------- generic transpose (+dtype-adaptive read) for Wo ----------------
__global__ __launch_bounds__(256) void transpose_cvt(
    const void* __restrict__ in, bf16* __restrict__ out,
    long in_stride, long out_stride, const int* __restrict__ flag) {
  __shared__ float tile[32][33];
  int fm = *flag;
  int c0 = blockIdx.x * 32, r0 = blockIdx.y * 32;
  int tx = threadIdx.x, ty = threadIdx.y;
#pragma unroll
  for (int i = 0; i < 32; i += 8) {
    long idx = (long)(r0 + ty + i) * in_stride + c0 + tx;
    tile[ty + i][tx] = fm ? (float)((const bf16*)in)[idx] : ((const float*)in)[idx];
  }
  __syncthreads();
#pragma unroll
  for (int i = 0; i < 32; i += 8)
    out[(long)(c0 + ty + i) * out_stride + r0 + tx] = (bf16)tile[tx][ty + i];
}

// ---------------- GEMM (128x128, 256 thr) -- kept as proven fallback ----------------
#define BM 128
#define BN 128
#define BK 32

__global__ __launch_bounds__(256) void gemm_bt(
    const void* __restrict__ A, const bf16* __restrict__ Bt, void* __restrict__ C,
    int M, int N, int K, int ldc, int ncmax,
    bf16* __restrict__ vt_out, int vcol0,
    const int* __restrict__ flag, int adyn, int cdyn) {
  alignas(16) __shared__ bf16 la[2 * BM * BK];  // 2 x 8 KB, unpadded (DMA lane-linear)
  alignas(16) __shared__ bf16 lb[2 * BN * BK];  // 2 x 8 KB
  int fm = flag ? *flag : 1;
  bool af32 = adyn && !fm;
  bool cf32 = cdyn && !fm;
  int tid = threadIdx.x;
  int wave = tid >> 6, lane = tid & 63;
  int wr = wave >> 1, wc = wave & 1;
  int quad = lane >> 4, l16 = lane & 15;

  int nwg = (int)(gridDim.x * gridDim.y);
  int flat = (int)(blockIdx.y * gridDim.x + blockIdx.x);
  int cpx = nwg >> 3;
  int wk = (flat & 7) * cpx + (flat >> 3);
  int bx = wk % (int)gridDim.x, by = wk / (int)gridDim.x;
  int m0 = by * BM, n0 = bx * BN;

  f32x4 acc[4][4] = {};

  int sr = (wave << 4) + (lane >> 2);
  int sc = (((lane & 3) - (sr >> 1)) & 3) << 3;  // rotated source chunk (elems)
  const bf16* gb0 = Bt + (long)(n0 + sr) * K + sc;
  const bf16* gb1 = Bt + (long)(n0 + 64 + sr) * K + sc;
  int lo0 = (wave << 9);
  int lo1 = 2048 + (wave << 9);
  const bf16* ga0 = nullptr; const bf16* ga1 = nullptr;
  const float* gaf = nullptr;
  int fr = tid >> 1, fh = (tid & 1) << 4;
  if (af32) gaf = (const float*)A + (long)(m0 + fr) * K + fh;
  else { ga0 = (const bf16*)A + (long)(m0 + sr) * K + sc;
         ga1 = (const bf16*)A + (long)(m0 + 64 + sr) * K + sc; }
  int c0 = fh >> 3;
  int k2 = (fr >> 1) & 3;
  int ws0 = ((c0 + k2) & 3) << 3;
  int ws1 = ((c0 + 1 + k2) & 3) << 3;

  int nk = K / BK;

  auto cvtwrite = [&](const float4* f, int buf) {
    alignas(16) bf16 tt[16];
#pragma unroll
    for (int u = 0; u < 4; u++) {
      tt[4 * u] = (bf16)f[u].x; tt[4 * u + 1] = (bf16)f[u].y;
      tt[4 * u + 2] = (bf16)f[u].z; tt[4 * u + 3] = (bf16)f[u].w;
    }
    bf16* rowp = la + (buf << 12) + fr * BK;
    *(uint4*)(rowp + ws0) = *(uint4*)tt;
    *(uint4*)(rowp + ws1) = *(uint4*)(tt + 8);
  };
  auto compute = [&](int buf) {
    const bf16* baA = la + (buf << 12);
    const bf16* baB = lb + (buf << 12);
    bf16x8 afr[4], bfr[4];
#pragma unroll
    for (int i = 0; i < 4; i++) {
      int rowA = (wr << 6) + (i << 4) + l16;
      afr[i] = *(const bf16x8*)(baA + rowA * BK + (((quad + (rowA >> 1)) & 3) << 3));
    }
#pragma unroll
    for (int j = 0; j < 4; j++) {
      int rowB = (wc << 6) + (j << 4) + l16;
      bfr[j] = *(const bf16x8*)(baB + rowB * BK + (((quad + (rowB >> 1)) & 3) << 3));
    }
#pragma unroll
    for (int i = 0; i < 4; i++)
#pragma unroll
      for (int j = 0; j < 4; j++)
        acc[i][j] = __builtin_amdgcn_mfma_f32_16x16x32_bf16(afr[i], bfr[j], acc[i][j], 0, 0, 0);
  };

  gload16(gb0, lb + lo0);
  gload16(gb1, lb + lo1);
  if (af32) {
    float4 f0[4];
#pragma unroll
    for (int u = 0; u < 4; u++) f0[u] = *(const float4*)(gaf + 4 * u);
    cvtwrite(f0, 0);
  } else {
    gload16(ga0, la + lo0);
    gload16(ga1, la + lo1);
  }
  __syncthreads();

  for (int t = 0; t < nk; ++t) {
    int cur = t & 1, nxt = cur ^ 1;
    bool hasnext = (t + 1 < nk);
    float4 f[4];
    if (hasnext) {
      int k0 = (t + 1) * BK;
      gload16(gb0 + k0, lb + (nxt << 12) + lo0);
      gload16(gb1 + k0, lb + (nxt << 12) + lo1);
      if (af32) {
        const float* fp = gaf + k0;
#pragma unroll
        for (int u = 0; u < 4; u++) f[u] = *(const float4*)(fp + 4 * u);
      } else {
        gload16(ga0 + k0, la + (nxt << 12) + lo0);
        gload16(ga1 + k0, la + (nxt << 12) + lo1);
      }
    }

    compute(cur);

    if (hasnext && af32) cvtwrite(f, nxt);
    __syncthreads();
  }

  if (vt_out && n0 >= vcol0) {
#pragma unroll
    for (int i = 0; i < 4; i++)
#pragma unroll
      for (int j = 0; j < 4; j++) {
        int col = n0 + (wc << 6) + (j << 4) + l16;
        int hdg = col - vcol0;
        int row0 = m0 + (wr << 6) + (i << 4) + (quad << 2);
        int bb = row0 >> 11, s = row0 & 2047;
        ushort4 p;
        p.x = bfb(acc[i][j][0]); p.y = bfb(acc[i][j][1]);
        p.z = bfb(acc[i][j][2]); p.w = bfb(acc[i][j][3]);
        *(ushort4*)(vt_out + (((long)(bb * 512 + hdg)) << 11) + s) = p;
      }
  } else {
#pragma unroll
    for (int i = 0; i < 4; i++)
#pragma unroll
      for (int j = 0; j < 4; j++) {
        int col = n0 + (wc << 6) + (j << 4) + l16;
        if (col >= ncmax) continue;
#pragma unroll
        for (int r = 0; r < 4; r++) {
          long row = m0 + (wr << 6) + (i << 4) + (quad << 2) + r;
          float v = acc[i][j][r];
          if (cf32) ((float*)C)[row * ldc + col] = v;
          else      ((bf16*)C)[row * ldc + col] = (bf16)v;
        }
      }
  }
}

// ---------------- GEMM wide: 128M x 256N, BK=32, 512 thr / 8 waves ----------------
// Used for BOTH gemm1 (A=xb, vt_out path) and gemm2 (A=attno, cdyn C-dtype).
// A is always bf16 at both call sites (adyn=0) -> pure-DMA A path.
#define WBM 128
#define WBN 256
#define WBK 32

__global__ __launch_bounds__(512, 4) void gemm_bt_wide(
    const void* __restrict__ A, const bf16* __restrict__ Bt, void* __restrict__ C,
    int K, int ldc, int ncmax,
    bf16* __restrict__ vt_out, int vcol0,
    const int* __restrict__ flag, int adyn, int cdyn) {
  alignas(16) __shared__ bf16 la[2 * WBM * WBK];  // 2 x 8 KB
  alignas(16) __shared__ bf16 lb[2 * WBN * WBK];  // 2 x 16 KB  (48 KB total)
  int fm = flag ? *flag : 1;
  bool af32 = adyn && !fm;
  bool cf32 = cdyn && !fm;
  int tid = threadIdx.x;
  int wave = tid >> 6, lane = tid & 63;
  int wm = wave >> 2, wn = wave & 3;  // 2M x 4N wave grid
  int quad = lane >> 4, l16 = lane & 15;

  // T1: XCD-aware block swizzle (nwg % 8 == 0 at both call sites)
  int nwg = (int)(gridDim.x * gridDim.y);
  int flat = (int)(blockIdx.y * gridDim.x + blockIdx.x);
  int cpx = nwg >> 3;
  int wk = (flat & 7) * cpx + (flat >> 3);
  int bx = wk % (int)gridDim.x, by = wk / (int)gridDim.x;
  int m0 = by * WBM, n0 = bx * WBN;

  f32x4 acc[4][4] = {};

  const bf16* gb[2];
  int lbo[2];
#pragma unroll
  for (int u = 0; u < 2; u++) {
    int sr2 = (wave << 5) + (u << 4) + (lane >> 2);
    int sc2 = (((lane & 3) - (sr2 >> 1)) & 3) << 3;  // rotated source chunk
    gb[u] = Bt + (long)(n0 + sr2) * K + sc2;
    lbo[u] = ((wave << 5) + (u << 4)) << 5;  // row_base * 32 elems (lane-linear dest)
  }
  const bf16* gaB = nullptr;
  const float* gaf = nullptr;
  int lao = (wave << 4) << 5;
  int fr = tid >> 2, fc = tid & 3;
  int wso = 0;
  if (af32) {
    gaf = (const float*)A + (long)(m0 + fr) * K + (fc << 3);
    wso = (fr << 5) + ((((fc) + (fr >> 1)) & 3) << 3);
  } else {
    int ra = (wave << 4) + (lane >> 2);
    int sca = (((lane & 3) - (ra >> 1)) & 3) << 3;
    gaB = (const bf16*)A + (long)(m0 + ra) * K + sca;
  }

  int nk = K / WBK;

  auto cvtwrite = [&](const float4* f, int buf) {
    alignas(16) bf16 tt[8];
    tt[0] = (bf16)f[0].x; tt[1] = (bf16)f[0].y; tt[2] = (bf16)f[0].z; tt[3] = (bf16)f[0].w;
    tt[4] = (bf16)f[1].x; tt[5] = (bf16)f[1].y; tt[6] = (bf16)f[1].z; tt[7] = (bf16)f[1].w;
    *(uint4*)(la + (buf << 12) + wso) = *(uint4*)tt;
  };
  auto compute = [&](int buf) {
    const bf16* baA = la + (buf << 12);
    const bf16* baB = lb + (buf << 13);
    bf16x8 afr[4], bfr[4];
#pragma unroll
    for (int i = 0; i < 4; i++) {
      int rowA = (wm << 6) + (i << 4) + l16;
      afr[i] = *(const bf16x8*)(baA + (rowA << 5) + (((quad + (rowA >> 1)) & 3) << 3));
    }
#pragma unroll
    for (int j = 0; j < 4; j++) {
      int rowB = (wn << 6) + (j << 4) + l16;
      bfr[j] = *(const bf16x8*)(baB + (rowB << 5) + (((quad + (rowB >> 1)) & 3) << 3));
    }
#pragma unroll
    for (int i = 0; i < 4; i++)
#pragma unroll
      for (int j = 0; j < 4; j++)
        acc[i][j] = __builtin_amdgcn_mfma_f32_16x16x32_bf16(afr[i], bfr[j], acc[i][j], 0, 0, 0);
  };

  // ---- prologue ----
  gload16(gb[0], lb + lbo[0]);
  gload16(gb[1], lb + lbo[1]);
  if (af32) {
    float4 f0[2];
    f0[0] = *(const float4*)gaf;
    f0[1] = *(const float4*)(gaf + 4);
    cvtwrite(f0, 0);
  } else {
    gload16(gaB, la + lao);
  }
  __syncthreads();

  // ---- main loop: ONE barrier per K-step; stage t+1 overlaps compute t ----
  for (int t = 0; t < nk; ++t) {
    int cur = t & 1, nxt = cur ^ 1;
    bool hasnext = (t + 1 < nk);
    float4 f[2];
    if (hasnext) {
      int k0 = (t + 1) * WBK;
      gload16(gb[0] + k0, lb + (nxt << 13) + lbo[0]);
      gload16(gb[1] + k0, lb + (nxt << 13) + lbo[1]);
      if (af32) {
        f[0] = *(const float4*)(gaf + k0);
        f[1] = *(const float4*)(gaf + k0 + 4);
      } else {
        gload16(gaB + k0, la + (nxt << 12) + lao);
      }
    }

    compute(cur);

    if (hasnext && af32) cvtwrite(f, nxt);
    __syncthreads();
  }

  // epilogue: col = n0 + wn*64 + j*16 + l16; row = m0 + wm*64 + i*16 + quad*4 + r
  if (vt_out && n0 >= vcol0) {
#pragma unroll
    for (int i = 0; i < 4; i++)
#pragma unroll
      for (int j = 0; j < 4; j++) {
        int col = n0 + (wn << 6) + (j << 4) + l16;
        int hdg = col - vcol0;                            // 0..511 = kh*128+hd
        int row0 = m0 + (wm << 6) + (i << 4) + (quad << 2);
        int bb = row0 >> 11, s = row0 & 2047;
        ushort4 p;
        p.x = bfb(acc[i][j][0]); p.y = bfb(acc[i][j][1]);
        p.z = bfb(acc[i][j][2]); p.w = bfb(acc[i][j][3]);
        *(ushort4*)(vt_out + (((long)(bb * 512 + hdg)) << 11) + s) = p;
      }
  } else {
#pragma unroll
    for (int i = 0; i < 4; i++)
#pragma unroll
      for (int j = 0; j < 4; j++) {
        int col = n0 + (wn << 6) + (j << 4) + l16;
        if (col >= ncmax) continue;
#pragma unroll
        for (int r = 0; r < 4; r++) {
          long row = m0 + (wm << 6) + (i << 4) + (quad << 2) + r;
          float v = acc[i][j][r];
          if (cf32) ((float*)C)[row * ldc + col] = v;
          else      ((bf16*)C)[row * ldc + col] = (bf16)v;
        }
      }
  }
}

// ---------------- RoPE + scatter (Q pre-scaled by 1/sqrt(d)) ----------------
__global__ __launch_bounds__(256) void rope_scatter(
    const bf16* __restrict__ qkv, bf16* __restrict__ Q, bf16* __restrict__ Ko) {
  int row = blockIdx.x;  // b*S + s
  int b = row >> 11, s = row & 2047;
  int tid = threadIdx.x;
  int i = tid & 63;
  const bf16* src = qkv + (long)row * QKW;
  float theta = __expf(-0.14391156831212787f * (float)i);  // 10000^(-2i/128)
  float sn, cs;
  sincosf((float)s * theta, &sn, &cs);
#pragma unroll
  for (int it = 0; it < 4; ++it) {
    int h = (tid + it * 256) >> 6;  // 0..15 over the 4 iterations
    unsigned v = *(const unsigned*)(src + h * 128 + 2 * i);
    float x1 = __uint_as_float(v << 16);
    float x2 = __uint_as_float(v & 0xFFFF0000u);
    long qb = ((long)(b * H_ + h) * S_ + s) * HD_;
    Q[qb + i]      = (bf16)((x1 * cs - x2 * sn) * SCALE);
    Q[qb + 64 + i] = (bf16)((x1 * sn + x2 * cs) * SCALE);
  }
  {
    int kh = tid >> 6;
    unsigned v = *(const unsigned*)(src + 2048 + kh * 128 + 2 * i);
    float x1 = __uint_as_float(v << 16);
    float x2 = __uint_as_float(v & 0xFFFF0000u);
    long kb = ((long)(b * HKV_ + kh) * S_ + s) * HD_;
    Ko[kb + i]      = (bf16)(x1 * cs - x2 * sn);
    Ko[kb + 64 + i] = (bf16)(x1 * sn + x2 * cs);
  }
}

// ---------------- flash attention (R10 version -- REVERTED from R11's V-direct) ----------------
// V staged in LDS (the staging IS the coalescing/transpose layer: direct global V
// reads are 32 scattered 8B loads per tile per wave -> R11 regressed 85->277 us).
// Paired-causal 512 blocks, XCD partition blockIdx%8 = (b,kh).
#define KTILE 8192  // 64 rows x 128 elems
#define VTILE 8192  // 128 rows x 64 elems

__global__ __launch_bounds__(256) void attn_kernel(
    const bf16* __restrict__ Q, const bf16* __restrict__ K,
    const bf16* __restrict__ Vt, bf16* __restrict__ O) {
  alignas(16) __shared__ bf16 Ks[2 * KTILE];  // 32 KB
  alignas(16) __shared__ bf16 Vs[2 * VTILE];  // 32 KB
  int bi = (int)blockIdx.x;        // 512 blocks, 1-D
  int cb = bi & 7;                 // XCD selector = (b, kh)
  int b = cb >> 2, kh = cb & 3;
  int r = bi >> 3;
  int qt0 = r >> 2;                // 0..15; paired with 31-qt0
  int h = kh * 4 + (r & 3);
  int tid = threadIdx.x, wave = tid >> 6, lane = tid & 63;
  int quad = lane >> 4, l16 = lane & 15;
  const bf16* Kg = K + ((long)(b * HKV_ + kh) * S_) * HD_;
  const bf16* Vg = Vt + ((long)(b * HKV_ + kh) * HD_) * S_;

  int kgo[4], vgo[4], klo[4], vlo[4];
#pragma unroll
  for (int u = 0; u < 4; u++) {
    int i = u * 4 + wave;
    int rr = i * 4 + quad;
    int c = l16 ^ (rr & 15);
    kgo[u] = rr * HD_ + c * 8;
    klo[u] = i * 512;
    int v = i * 8 + (lane >> 3);
    int cv = (lane & 7) ^ (v & 7);
    vgo[u] = v * S_ + cv * 8;
    vlo[u] = i * 512;
  }

  for (int hf = 0; hf < 2; ++hf) {
    int qt = hf ? 31 - qt0 : qt0;
    int q0 = qt * 64;
    const bf16* Qg = Q + ((long)(b * H_ + h) * S_ + q0) * HD_;

    bf16x8 qb[4];
    {
      const bf16* qrow = Qg + (wave * 16 + l16) * HD_ + quad * 8;
#pragma unroll
      for (int kk = 0; kk < 4; kk++) qb[kk] = *(const bf16x8*)(qrow + kk * 32);
    }

    if (hf) __syncthreads();

#pragma unroll
    for (int u = 0; u < 4; u++) {
      gload16(Kg + kgo[u], Ks + klo[u]);
      gload16(Vg + vgo[u], Vs + vlo[u]);
    }

    f32x4 Of[8] = {};
    float m_run = NEGINF, l_run = 0.f;

    for (int kt = 0; kt <= qt; ++kt) {
      __syncthreads();
      int p = kt & 1;
      if (kt < qt) {
        const bf16* kn = Kg + (long)(kt + 1) * 8192;
        const bf16* vn = Vg + (long)(kt + 1) * 64;
        bf16* kd = Ks + (p ^ 1) * KTILE;
        bf16* vd = Vs + (p ^ 1) * VTILE;
#pragma unroll
        for (int u = 0; u < 4; u++) {
          gload16(kn + kgo[u], kd + klo[u]);
          gload16(vn + vgo[u], vd + vlo[u]);
        }
      }
      const bf16* kc = Ks + p * KTILE;
      const bf16* vc = Vs + p * VTILE;

      bool diag = (kt == qt);
      f32x4 sf[4];
      __builtin_amdgcn_s_setprio(1);
#pragma unroll
      for (int jb = 0; jb < 4; jb++) {
        if (diag && jb > wave) {
          sf[jb] = (f32x4){NEGINF, NEGINF, NEGINF, NEGINF};
        } else {
          f32x4 a = {};
          const bf16* kbase = kc + (jb * 16 + l16) * 128;
#pragma unroll
          for (int kk = 0; kk < 4; kk++) {
            bf16x8 kf = *(const bf16x8*)(kbase + (((kk * 4 + quad) ^ l16) * 8));
            a = __builtin_amdgcn_mfma_f32_16x16x32_bf16(kf, qb[kk], a, 0, 0, 0);
          }
          sf[jb] = a;
        }
      }
      __builtin_amdgcn_s_setprio(0);
      if (diag) {
#pragma unroll
        for (int jb = 0; jb < 4; jb++)
          if (jb == wave) {
#pragma unroll
            for (int r2 = 0; r2 < 4; r2++)
              if (quad * 4 + r2 > l16) sf[jb][r2] = NEGINF;
          }
      }

      float mx = NEGINF;
#pragma unroll
      for (int jb = 0; jb < 4; jb++)
#pragma unroll
        for (int r2 = 0; r2 < 4; r2++) mx = fmaxf(mx, sf[jb][r2]);
      mx = fmaxf(mx, __shfl_xor(mx, 16));
      mx = fmaxf(mx, __shfl_xor(mx, 32));
      if (__any(mx > m_run + 8.0f)) {
        float mnew = fmaxf(m_run, mx);
        float alpha = __expf(m_run - mnew);
        m_run = mnew;
        l_run *= alpha;
#pragma unroll
        for (int n = 0; n < 8; n++) Of[n] *= alpha;
      }

      float ls = 0.f;
      s16x4 pk[4];
#pragma unroll
      for (int jb = 0; jb < 4; jb++) {
        float p0 = __expf(sf[jb][0] - m_run);
        float p1 = __expf(sf[jb][1] - m_run);
        float p2 = __expf(sf[jb][2] - m_run);
        float p3 = __expf(sf[jb][3] - m_run);
        ls += (p0 + p1) + (p2 + p3);
        s16x4 t;
        t.x = (short)bfb(p0); t.y = (short)bfb(p1);
        t.z = (short)bfb(p2); t.w = (short)bfb(p3);
        pk[jb] = t;
      }
      l_run += ls;

      __builtin_amdgcn_s_setprio(1);
#pragma unroll
      for (int jb = 0; jb < 4; jb++) {
        if (diag && jb > wave) continue;
#pragma unroll
        for (int n = 0; n < 8; n++) {
          int v = n * 16 + l16;
          const bf16* va_p = vc + v * 64 + (((jb * 2 + (quad >> 1)) ^ (l16 & 7)) * 8) + (quad & 1) * 4;
          s16x4 va = *(const s16x4*)va_p;
          Of[n] = __builtin_amdgcn_mfma_f32_16x16x16bf16_1k(va, pk[jb], Of[n], 0, 0, 0);
        }
      }
      __builtin_amdgcn_s_setprio(0);
    }

    l_run += __shfl_xor(l_run, 16);
    l_run += __shfl_xor(l_run, 32);
    float inv = 1.0f / fmaxf(l_run, 1e-30f);
    bf16* Ob = O + ((long)(b * S_) + q0 + wave * 16 + l16) * D_ + h * HD_;
#pragma unroll
    for (int n = 0; n < 8; n++) {
      ushort4 w;
      w.x = bfb(Of[n][0] * inv); w.y = bfb(Of[n][1] * inv);
      w.z = bfb(Of[n][2] * inv); w.w = bfb(Of[n][3] * inv);
      *(ushort4*)(Ob + n * 16 + quad * 4) = w;
    }
  }
}

// ---------------- launch ----------------
extern "C" void kernel_launch(void* const* d_in, const int* in_sizes, int n_in,
                              void* d_out, int out_size, void* d_ws, size_t ws_size,
                              hipStream_t stream) {
  const void* x  = d_in[0];
  const void* Wq = d_in[1];
  const void* Wk = d_in[2];
  const void* Wv = d_in[3];
  const void* Wo = d_in[4];
  bf16* ws = (bf16*)d_ws;
  int* flag = (int*)d_ws;

  // workspace (bf16 elem offsets), peak 23,068,688 elems = 46.1 MB (proven)
  bf16* qkv   = ws + 16;        // 4096 x 2560          gemm1 -> rope
  bf16* Vtb   = ws + 10485776;  // 2 x 512 x 2048       gemm1 epilogue -> attn
  bf16* Qb    = ws + 12582928;  // 2x16x2048x128        rope -> attn
  bf16* wqkvT = ws + 12582928;  // 3072x2048 (overlaps Qb; dead before rope writes)
  bf16* Kb    = ws + 20971536;  // 2x4x2048x128         rope -> attn
  bf16* attno = ws + 16;        // reuse qkv            attn -> gemm2
  bf16* woT   = ws + 10485776;  // reuse Vtb/Qb region  (transposed after attn)
  bf16* xb    = (bf16*)d_out;   // x in bf16 (d_out scratch; dead before gemm2 writes)

  dim3 tb(32, 8);
  detect_dtype<<<1, 256, 0, stream>>>((const unsigned*)x, flag);
  cast_x<<<4096, 256, 0, stream>>>(x, xb, flag);
  transpose_qkvw<<<dim3(64, 64, 3), tb, 0, stream>>>(Wq, Wk, Wv, wqkvT, flag);
  // qkv = xb @ [Wq|Wk|Wv]; q,k cols -> qkv (ldc 2560), v cols -> Vtb transposed
  gemm_bt_wide<<<dim3(QKVW / WBN, (B_ * S_) / WBM), 512, 0, stream>>>(
      xb, wqkvT, qkv, D_, QKW, QKW, Vtb, QKW, nullptr, 0, 0);
  rope_scatter<<<B_ * S_, 256, 0, stream>>>(qkv, Qb, Kb);
  // paired-causal 1-D grid: 512 blocks; low 3 bits = (b,kh) -> XCD partition
  attn_kernel<<<dim3(512, 1, 1), 256, 0, stream>>>(Qb, Kb, Vtb, attno);
  transpose_cvt<<<dim3(64, 64, 1), tb, 0, stream>>>(Wo, woT, 2048, 2048, flag);
  // out = attno @ Wo via the wide kernel (grid 8x32 = 256, %8==0; C dtype per flag)
  gemm_bt_wide<<<dim3(D_ / WBN, (B_ * S_) / WBM), 512, 0, stream>>>(
      attno, woT, d_out, D_, D_, D_, nullptr, 0, flag, 0, 1);
}